// Round 4
// baseline (81.011 us; speedup 1.0000x reference)
//
#include <hip/hip_runtime.h>

// L1 attention: attn[b,s,t,h] = -sum_w |q[b,s,h,w] - k[b,t,h,w]| / sqrt(W)
// B=1, S=T=1024, H=8, W=32, fp32 in / fp32 out.
//
// Round 4: push LDS traffic below the VALU floor via a 4-row k register tile.
// - thread = (h, tsub) owns FOUR k rows (t0 + {0,32,64,96} + tsub): 128 VGPR.
//   q-LDS ratio = 0.5 B per VALU op (268 MB total ~= 3.9 us, under the 7.5 us
//   VALU floor). Per CU per si-round: LDS 768 cy < VALU 1024 cy -> VALU-bound.
// - q tile 16 s x 8 h x 128 B = 16 KB LDS, chunk-XOR swizzle (j ^ h):
//   broadcast reads conflict-free.
// - ~200 VGPR -> __launch_bounds__(256,2): 2 waves/SIMD, 2 blocks/CU,
//   16 indep acc chains/thread for ILP latency hiding. No barrier in loop.
// - nontemporal stores: keep the 32 MB out stream from evicting q/k (R2 bug).

constexpr int S_DIM = 1024;
constexpr int T_DIM = 1024;
constexpr int H_DIM = 8;
constexpr int W_DIM = 32;
constexpr int TB = 128;  // t per block (4 per thread)
constexpr int SB = 16;   // s per block
constexpr int CT = 4;    // k rows per thread

__global__ __launch_bounds__(256, 2)
void l1attn_kernel(const float* __restrict__ q,
                   const float* __restrict__ k,
                   float* __restrict__ out) {
    const int tid  = threadIdx.x;
    const int h    = tid & 7;
    const int tsub = tid >> 3;                 // 0..31
    const int t0   = blockIdx.x * TB;
    const int s0   = blockIdx.y * SB;

    __shared__ float4 qlds[SB * H_DIM * (W_DIM / 4)];  // 1024 float4 = 16 KB

    // ---- four k rows -> 128 VGPRs, reused for all 16 s ----
    float kreg[CT][W_DIM];
    #pragma unroll
    for (int u = 0; u < CT; ++u) {
        const float4* krow =
            (const float4*)(k + ((t0 + u * 32 + tsub) * H_DIM + h) * W_DIM);
        #pragma unroll
        for (int j = 0; j < 8; ++j) {
            float4 v = krow[j];
            kreg[u][4 * j + 0] = v.x;
            kreg[u][4 * j + 1] = v.y;
            kreg[u][4 * j + 2] = v.z;
            kreg[u][4 * j + 3] = v.w;
        }
    }

    // ---- stage q tile (contiguous 16 KB) into swizzled LDS ----
    const float4* q4 = (const float4*)(q + (size_t)s0 * H_DIM * W_DIM);
    #pragma unroll
    for (int p = 0; p < 4; ++p) {
        int f = p * 256 + tid;   // float4 index, 0..1023
        int r = f >> 3;          // row = si*8 + h_row
        int j = f & 7;           // 16B chunk in row
        qlds[r * 8 + (j ^ (r & 7))] = q4[f];
    }
    __syncthreads();

    const float nscale = -0.17677669529663688f;  // -1/sqrt(32)

    for (int si = 0; si < SB; ++si) {
        const float4* qrow = qlds + (si * H_DIM + h) * 8;
        float4 qv[8];
        #pragma unroll
        for (int j = 0; j < 8; ++j) qv[j] = qrow[j ^ h];

        float a[CT][4];
        #pragma unroll
        for (int u = 0; u < CT; ++u)
            a[u][0] = a[u][1] = a[u][2] = a[u][3] = 0.f;

        #pragma unroll
        for (int j = 0; j < 8; ++j) {
            #pragma unroll
            for (int u = 0; u < CT; ++u) {
                a[u][0] += fabsf(qv[j].x - kreg[u][4 * j + 0]);
                a[u][1] += fabsf(qv[j].y - kreg[u][4 * j + 1]);
                a[u][2] += fabsf(qv[j].z - kreg[u][4 * j + 2]);
                a[u][3] += fabsf(qv[j].w - kreg[u][4 * j + 3]);
            }
        }

        const int s = s0 + si;
        #pragma unroll
        for (int u = 0; u < CT; ++u) {
            const float r =
                ((a[u][0] + a[u][1]) + (a[u][2] + a[u][3])) * nscale;
            __builtin_nontemporal_store(
                r, &out[(s * T_DIM + t0 + u * 32 + tsub) * H_DIM + h]);
        }
    }
}

extern "C" void kernel_launch(void* const* d_in, const int* in_sizes, int n_in,
                              void* d_out, int out_size, void* d_ws, size_t ws_size,
                              hipStream_t stream) {
    const float* q = (const float*)d_in[0];
    const float* k = (const float*)d_in[1];
    float* out = (float*)d_out;
    dim3 grid(T_DIM / TB, S_DIM / SB);  // (8, 64) = 512 blocks
    l1attn_kernel<<<grid, dim3(256, 1, 1), 0, stream>>>(q, k, out);
}